// Round 11
// baseline (197.366 us; speedup 1.0000x reference)
//
#include <hip/hip_runtime.h>

// Polyphase 2x upsample, depthwise 12-tap, reflect pad, fp32.
// out[b,c,oh,ow] = 4 * sum_{m,n=0..5} x[b,c,reflect(q_y+py+m-3),reflect(q_x+px+n-3)]
//                       * filt[11-py-2m][11-px-2n],  oh=2*q_y+py, ow=2*q_x+px
//
// R9->R10: kernel was VALU-issue-bound (576 scalar v_fma; R8/R9 occupancy work
// was neutral). Halve FMA issue via packed fp32 (v_pk_fma_f32):
//  - each acc is a v2f partial accumulator over n-pairs {0,1}{2,3}{4,5};
//    halves summed in epilogue -> 288 packed FMAs
//  - source pairs read directly from LDS (ds_read_b64 / ds_read2_b32)
//  - filter packed into d_ws by a prep kernel as (py,px,m,j) float2 pairs,
//    pre-scaled by 4 -> wave-uniform s_load_dwordx2 operands

#define S 40             // slab row stride in words
#define WREG 576         // padded wave slab: 9 chunks x 64 words (14x40 used)

typedef float v2f __attribute__((ext_vector_type(2)));
typedef __attribute__((address_space(3))) void lds_t;
typedef __attribute__((address_space(1))) const void gm_t;

__global__ void filter_prep(const float* __restrict__ filt, float* __restrict__ ws)
{
    int p = threadIdx.x;            // pair index 0..71
    if (p < 72) {
        int j = p % 3, m = (p / 3) % 6, px = (p / 18) & 1, py = p / 36;
        int row = (11 - py - 2 * m) * 12;
        ws[2 * p]     = 4.0f * filt[row + 11 - px - 4 * j];   // n = 2j
        ws[2 * p + 1] = 4.0f * filt[row + 9  - px - 4 * j];   // n = 2j+1
    }
}

#define XP(c) (((c) & 1) ? o[((c) - 1) >> 1] : e[(c) >> 1])

__global__ __launch_bounds__(256, 6) void upsample2d_kernel(
    const float* __restrict__ x, const v2f* __restrict__ ft,
    float* __restrict__ out)
{
    __shared__ float s_in[4 * WREG];      // 9216 B

    const int tx = threadIdx.x, ty = threadIdx.y;
    const int w    = ty >> 2;             // wave id 0..3
    const int lane = (ty & 3) * 16 + tx;  // HW lane id within wave
    const int bc  = blockIdx.z;           // fused (batch,channel) 0..255
    const int boy = blockIdx.y, box = blockIdx.x;

    const float* xc = x + (size_t)bc * 65536;
    const int row0 = boy * 32 + w * 8 - 3;
    const int col0 = box * 32 - 3;

    float* sw = s_in + w * WREG;

    // ---- staging: 9 x global_load_lds, linear wave-private slab ----
    #pragma unroll
    for (int k = 0; k < 9; ++k) {
        int j = lane + 64 * k;
        int r = (j * 1639) >> 16;         // j / 40
        int c = j - r * 40;
        int gy = row0 + r, gx = col0 + c;
        gy = gy < 0 ? -gy : gy;  gy = gy > 255 ? 510 - gy : gy;
        gx = gx < 0 ? -gx : gx;  gx = gx > 255 ? 510 - gx : gx;
        __builtin_amdgcn_global_load_lds((gm_t*)(xc + gy * 256 + gx),
                                         (lds_t*)(sw + 64 * k), 4, 0, 0);
    }
    asm volatile("s_waitcnt vmcnt(0)" ::: "memory");   // wave-private: no barrier

    // ---- packed-pair compute: 288 x v_pk_fma_f32 ----
    const int xb = w * WREG + (2 * (ty & 3)) * S + 2 * tx;
    v2f acc2[4][4] = {};                  // [oy][ox] 2-wide partial sums over n
    #pragma unroll
    for (int r = 0; r < 8; ++r) {
        const int rb = xb + r * S;
        v2f e[4], o[3];
        #pragma unroll
        for (int j = 0; j < 4; ++j)       // even pairs: cols (2j, 2j+1), 8B aligned
            e[j] = *reinterpret_cast<const v2f*>(&s_in[rb + 2 * j]);
        #pragma unroll
        for (int j = 0; j < 3; ++j) {     // odd pairs: cols (2j+1, 2j+2)
            o[j].x = s_in[rb + 2 * j + 1];
            o[j].y = s_in[rb + 2 * j + 2];
        }
        #pragma unroll
        for (int qy = 0; qy < 2; ++qy)
        #pragma unroll
        for (int py = 0; py < 2; ++py) {
            const int m = r - qy - py;    // compile-time after unroll
            if (m >= 0 && m <= 5) {
                #pragma unroll
                for (int px = 0; px < 2; ++px) {
                    const int base = ((py * 2 + px) * 6 + m) * 3;
                    #pragma unroll
                    for (int j = 0; j < 3; ++j) {
                        const v2f f = ft[base + j];               // s_load_dwordx2
                        acc2[2 * qy + py][px] =
                            __builtin_elementwise_fma(XP(px + 2 * j), f,
                                                      acc2[2 * qy + py][px]);
                        acc2[2 * qy + py][2 + px] =
                            __builtin_elementwise_fma(XP(1 + px + 2 * j), f,
                                                      acc2[2 * qy + py][2 + px]);
                    }
                }
            }
        }
    }

    // ---- epilogue: sum pair halves (scale already folded into ft) ----
    float* oc = out + (size_t)bc * 262144;
    const int OY0 = boy * 64 + 4 * ty;
    const int OX  = box * 64 + 4 * tx;
    #pragma unroll
    for (int oy = 0; oy < 4; ++oy) {
        float4 v = make_float4(acc2[oy][0].x + acc2[oy][0].y,
                               acc2[oy][1].x + acc2[oy][1].y,
                               acc2[oy][2].x + acc2[oy][2].y,
                               acc2[oy][3].x + acc2[oy][3].y);
        *reinterpret_cast<float4*>(&oc[(size_t)(OY0 + oy) * 512 + OX]) = v;
    }
}

extern "C" void kernel_launch(void* const* d_in, const int* in_sizes, int n_in,
                              void* d_out, int out_size, void* d_ws, size_t ws_size,
                              hipStream_t stream) {
    const float* x    = (const float*)d_in[0];   // (4,64,256,256) fp32
    const float* filt = (const float*)d_in[1];   // (12,12) fp32
    float* out = (float*)d_out;                  // (4,64,512,512) fp32
    float* ws  = (float*)d_ws;                   // 576 B packed filter table

    filter_prep<<<dim3(1), dim3(128), 0, stream>>>(filt, ws);

    dim3 grid(8, 8, 256);   // 8x8 tiles of 64x64; z = fused (batch,channel)
    dim3 block(16, 16, 1);
    upsample2d_kernel<<<grid, block, 0, stream>>>(x, (const v2f*)ws, out);
}

// Round 12
// 88.763 us; speedup vs baseline: 2.2235x; 2.2235x over previous
//
#include <hip/hip_runtime.h>

// Polyphase 2x upsample, depthwise 12-tap, reflect pad, fp32.
// out[b,c,oh,ow] = 4 * sum_{m,n=0..5} x[b,c,reflect(q_y+py+m-3),reflect(q_x+px+n-3)]
//                       * filt[11-py-2m][11-px-2n],  oh=2*q_y+py, ow=2*q_x+px
//
// R11->R12: R11's packed version SPILLED (VGPR=40, WRITE_SIZE 601MB = scratch).
// Same packed-FMA idea, half the accumulator state: pair over OUTPUT qx.
//  - accp[oy][px] = (out[oy][px], out[oy][2+px]) -> 8 v2f = 16 VGPRs (was 32)
//  - input operand = adjacent pair (x[c], x[c+1]) from LDS (same e/o reads)
//  - filter operand = (f,f): prep kernel duplicates each tap -> s_load_dwordx2
//  - launch_bounds(256,4): VGPR cap 128, spill impossible for ~50 live regs

#define S 40             // slab row stride in words
#define WREG 576         // padded wave slab: 9 chunks x 64 words (14x40 used)

typedef float v2f __attribute__((ext_vector_type(2)));
typedef __attribute__((address_space(3))) void lds_t;
typedef __attribute__((address_space(1))) const void gm_t;

__global__ void filter_prep(const float* __restrict__ filt, float* __restrict__ ws)
{
    int t = threadIdx.x;                 // scalar tap index 0..143
    if (t < 144) {
        int n = t % 6, m = (t / 6) % 6, px = (t / 36) & 1, py = t / 72;
        float f = 4.0f * filt[(11 - py - 2 * m) * 12 + (11 - px - 2 * n)];
        ws[2 * t]     = f;               // duplicated: (f,f) pair for v_pk_fma
        ws[2 * t + 1] = f;
    }
}

__global__ __launch_bounds__(256, 4) void upsample2d_kernel(
    const float* __restrict__ x, const v2f* __restrict__ ftp,
    float* __restrict__ out)
{
    __shared__ float s_in[4 * WREG];      // 9216 B

    const int tx = threadIdx.x, ty = threadIdx.y;
    const int w    = ty >> 2;             // wave id 0..3
    const int lane = (ty & 3) * 16 + tx;  // HW lane id within wave
    const int bc  = blockIdx.z;           // fused (batch,channel) 0..255
    const int boy = blockIdx.y, box = blockIdx.x;

    const float* xc = x + (size_t)bc * 65536;
    const int row0 = boy * 32 + w * 8 - 3;
    const int col0 = box * 32 - 3;

    float* sw = s_in + w * WREG;

    // ---- staging: 9 x global_load_lds, linear wave-private slab ----
    #pragma unroll
    for (int k = 0; k < 9; ++k) {
        int j = lane + 64 * k;
        int r = (j * 1639) >> 16;         // j / 40
        int c = j - r * 40;
        int gy = row0 + r, gx = col0 + c;
        gy = gy < 0 ? -gy : gy;  gy = gy > 255 ? 510 - gy : gy;
        gx = gx < 0 ? -gx : gx;  gx = gx > 255 ? 510 - gx : gx;
        __builtin_amdgcn_global_load_lds((gm_t*)(xc + gy * 256 + gx),
                                         (lds_t*)(sw + 64 * k), 4, 0, 0);
    }
    asm volatile("s_waitcnt vmcnt(0)" ::: "memory");   // wave-private: no barrier

    // ---- packed compute: accp[oy][px] = (out[oy][px], out[oy][2+px]) ----
    const int xb = w * WREG + (2 * (ty & 3)) * S + 2 * tx;
    v2f accp[4][2] = {};                  // 16 VGPRs total
    #pragma unroll
    for (int r = 0; r < 8; ++r) {
        const int rb = xb + r * S;
        v2f e[4], o[3];
        #pragma unroll
        for (int j = 0; j < 4; ++j)       // even pairs: cols (2j, 2j+1)
            e[j] = *reinterpret_cast<const v2f*>(&s_in[rb + 2 * j]);
        #pragma unroll
        for (int j = 0; j < 3; ++j) {     // odd pairs: cols (2j+1, 2j+2)
            o[j].x = s_in[rb + 2 * j + 1];
            o[j].y = s_in[rb + 2 * j + 2];
        }
        #pragma unroll
        for (int qy = 0; qy < 2; ++qy)
        #pragma unroll
        for (int py = 0; py < 2; ++py) {
            const int m = r - qy - py;    // compile-time after unroll
            if (m >= 0 && m <= 5) {
                #pragma unroll
                for (int px = 0; px < 2; ++px)
                #pragma unroll
                for (int n = 0; n < 6; ++n) {
                    const int c = px + n;                  // 0..6
                    const v2f xp = (c & 1) ? o[(c - 1) >> 1] : e[c >> 1];
                    const v2f f2 = ftp[((py * 2 + px) * 6 + m) * 6 + n];
                    accp[2 * qy + py][px] =
                        __builtin_elementwise_fma(xp, f2, accp[2 * qy + py][px]);
                }
            }
        }
    }

    // ---- epilogue: unpack qx pairs into float4 stores (scale in table) ----
    float* oc = out + (size_t)bc * 262144;
    const int OY0 = boy * 64 + 4 * ty;
    const int OX  = box * 64 + 4 * tx;
    #pragma unroll
    for (int oy = 0; oy < 4; ++oy) {
        float4 v = make_float4(accp[oy][0].x, accp[oy][1].x,
                               accp[oy][0].y, accp[oy][1].y);
        *reinterpret_cast<float4*>(&oc[(size_t)(OY0 + oy) * 512 + OX]) = v;
    }
}

extern "C" void kernel_launch(void* const* d_in, const int* in_sizes, int n_in,
                              void* d_out, int out_size, void* d_ws, size_t ws_size,
                              hipStream_t stream) {
    const float* x    = (const float*)d_in[0];   // (4,64,256,256) fp32
    const float* filt = (const float*)d_in[1];   // (12,12) fp32
    float* out = (float*)d_out;                  // (4,64,512,512) fp32
    float* ws  = (float*)d_ws;                   // 1152 B duplicated filter table

    filter_prep<<<dim3(1), dim3(256), 0, stream>>>(filt, ws);

    dim3 grid(8, 8, 256);   // 8x8 tiles of 64x64; z = fused (batch,channel)
    dim3 block(16, 16, 1);
    upsample2d_kernel<<<grid, block, 0, stream>>>(x, (const v2f*)ws, out);
}

// Round 13
// 86.488 us; speedup vs baseline: 2.2820x; 1.0263x over previous
//
#include <hip/hip_runtime.h>

// Polyphase 2x upsample, depthwise 12-tap, reflect pad, fp32.
// out[b,c,oh,ow] = 4 * sum_{m,n=0..5} x[b,c,reflect(q_y+py+m-3),reflect(q_x+px+n-3)]
//                       * filt[11-py-2m][11-px-2n],  oh=2*q_y+py, ow=2*q_x+px
//
// R12->R13: kill the stage->vmcnt(0)->compute convoy (memory idle ~25%).
// Each block does TWO tiles (same spatial tile/channel, batches b and b+2):
//  - goff[] reflect addresses computed ONCE, reused for both tiles
//  - all 18 global_load_lds issued up front (deep queue)
//  - vmcnt(9): compute tile0 while tile1's loads are in flight
//  - vmcnt(16): tile1 loads done, tile0 stores NOT drained (in-order retire)
// Compute core unchanged from R12 (288 v_pk_fma_f32, passed @ 88.8us).

#define S 40              // slab row stride in words
#define WREG 576          // per-wave slab: 9 chunks x 64 words (14x40 used)
#define BUF (4 * WREG)    // per-tile buffer: 4 waves

typedef float v2f __attribute__((ext_vector_type(2)));
typedef __attribute__((address_space(3))) void lds_t;
typedef __attribute__((address_space(1))) const void gm_t;

__global__ void filter_prep(const float* __restrict__ filt, float* __restrict__ ws)
{
    int t = threadIdx.x;                 // scalar tap index 0..143
    if (t < 144) {
        int n = t % 6, m = (t / 6) % 6, px = (t / 36) & 1, py = t / 72;
        float f = 4.0f * filt[(11 - py - 2 * m) * 12 + (11 - px - 2 * n)];
        ws[2 * t]     = f;               // duplicated (f,f) pair for v_pk_fma
        ws[2 * t + 1] = f;
    }
}

__global__ __launch_bounds__(256, 4) void upsample2d_kernel(
    const float* __restrict__ x, const v2f* __restrict__ ftp,
    float* __restrict__ out)
{
    __shared__ float s_in[2 * BUF];       // 18432 B: two tile buffers

    const int tx = threadIdx.x, ty = threadIdx.y;
    const int w    = ty >> 2;             // wave id 0..3
    const int lane = (ty & 3) * 16 + tx;  // HW lane id within wave
    const int bc0 = blockIdx.z;           // batch b=bc0>>6 (0..1), chan=bc0&63
    const int boy = blockIdx.y, box = blockIdx.x;

    // ---- reflect-mapped source offsets, computed once, shared by both tiles ----
    const int row0 = boy * 32 + w * 8 - 3;
    const int col0 = box * 32 - 3;
    int goff[9];
    #pragma unroll
    for (int k = 0; k < 9; ++k) {
        int j = lane + 64 * k;
        int r = (j * 1639) >> 16;         // j / 40
        int c = j - r * 40;
        int gy = row0 + r, gx = col0 + c;
        gy = gy < 0 ? -gy : gy;  gy = gy > 255 ? 510 - gy : gy;
        gx = gx < 0 ? -gx : gx;  gx = gx > 255 ? 510 - gx : gx;
        goff[k] = gy * 256 + gx;
    }

    const float* x0 = x + (size_t)bc0 * 65536;            // batch b
    const float* x1 = x0 + (size_t)128 * 65536;           // batch b+2
    float* sw0 = s_in + w * WREG;
    float* sw1 = s_in + BUF + w * WREG;

    // ---- issue ALL staging up front: 9 loads tile0, 9 loads tile1 ----
    #pragma unroll
    for (int k = 0; k < 9; ++k)
        __builtin_amdgcn_global_load_lds((gm_t*)(x0 + goff[k]),
                                         (lds_t*)(sw0 + 64 * k), 4, 0, 0);
    #pragma unroll
    for (int k = 0; k < 9; ++k)
        __builtin_amdgcn_global_load_lds((gm_t*)(x1 + goff[k]),
                                         (lds_t*)(sw1 + 64 * k), 4, 0, 0);

    const int xb = w * WREG + (2 * (ty & 3)) * S + 2 * tx;
    const int OY0 = boy * 64 + 4 * ty;
    const int OX  = box * 64 + 4 * tx;

    // ---- per-tile compute+store (R12 core), fully unrolled ----
    auto tile = [&](const int sbase, float* oc) {
        v2f accp[4][2] = {};              // (out[oy][px], out[oy][2+px])
        #pragma unroll
        for (int r = 0; r < 8; ++r) {
            const int rb = sbase + r * S;
            v2f e[4], o[3];
            #pragma unroll
            for (int j = 0; j < 4; ++j)
                e[j] = *reinterpret_cast<const v2f*>(&s_in[rb + 2 * j]);
            #pragma unroll
            for (int j = 0; j < 3; ++j) {
                o[j].x = s_in[rb + 2 * j + 1];
                o[j].y = s_in[rb + 2 * j + 2];
            }
            #pragma unroll
            for (int qy = 0; qy < 2; ++qy)
            #pragma unroll
            for (int py = 0; py < 2; ++py) {
                const int m = r - qy - py;
                if (m >= 0 && m <= 5) {
                    #pragma unroll
                    for (int px = 0; px < 2; ++px)
                    #pragma unroll
                    for (int n = 0; n < 6; ++n) {
                        const int c = px + n;
                        const v2f xp = (c & 1) ? o[(c - 1) >> 1] : e[c >> 1];
                        const v2f f2 = ftp[((py * 2 + px) * 6 + m) * 6 + n];
                        accp[2 * qy + py][px] =
                            __builtin_elementwise_fma(xp, f2, accp[2 * qy + py][px]);
                    }
                }
            }
        }
        #pragma unroll
        for (int oy = 0; oy < 4; ++oy) {
            float4 v = make_float4(accp[oy][0].x, accp[oy][1].x,
                                   accp[oy][0].y, accp[oy][1].y);
            *reinterpret_cast<float4*>(&oc[(size_t)(OY0 + oy) * 512 + OX]) = v;
        }
    };

    // tile 0: wait only its 9 loads (tile1's stay in flight)
    asm volatile("s_waitcnt vmcnt(9)" ::: "memory");
    tile(xb, out + (size_t)bc0 * 262144);

    // tile 1: 9 loads + 16 tile0-stores outstanding; in-order retire =>
    // vmcnt(16) guarantees the (older) 9 loads completed, stores not drained
    asm volatile("s_waitcnt vmcnt(16)" ::: "memory");
    tile(BUF + xb, out + (size_t)(bc0 + 128) * 262144);
}

extern "C" void kernel_launch(void* const* d_in, const int* in_sizes, int n_in,
                              void* d_out, int out_size, void* d_ws, size_t ws_size,
                              hipStream_t stream) {
    const float* x    = (const float*)d_in[0];   // (4,64,256,256) fp32
    const float* filt = (const float*)d_in[1];   // (12,12) fp32
    float* out = (float*)d_out;                  // (4,64,512,512) fp32
    float* ws  = (float*)d_ws;                   // 1152 B duplicated filter table

    filter_prep<<<dim3(1), dim3(256), 0, stream>>>(filt, ws);

    dim3 grid(8, 8, 128);   // 8x8 tiles; z = (batch 0..1, channel); +batch+2 in-kernel
    dim3 block(16, 16, 1);
    upsample2d_kernel<<<grid, block, 0, stream>>>(x, (const v2f*)ws, out);
}

// Round 15
// 85.031 us; speedup vs baseline: 2.3211x; 1.0171x over previous
//
#include <hip/hip_runtime.h>

// Polyphase 2x upsample, depthwise 12-tap, reflect pad, fp32.
// out[b,c,oh,ow] = 4 * sum_{m,n=0..5} x[b,c,reflect(q_y+py+m-3),reflect(q_x+px+n-3)]
//                       * filt[11-py-2m][11-px-2n],  oh=2*q_y+py, ow=2*q_x+px
//
// R14->R15: R14's register-synthesized odd pairs miscompiled (value-identical
// to R13 but failed) -> revert compute core to R13's exact proven form.
// New: block-cooperative staging to cut FETCH ~140->~95MB (y-halo shared
// across waves: one 38x40 slab per tile instead of 4x private 14x40).
// Raw s_barrier (no vmcnt(0) store-drain) + counted vmcnt keeps the
// dual-tile pipeline: 12 glds -> vmcnt(6)+bar -> tile0 -> vmcnt(16)+bar -> tile1.

#define S 40              // slab row stride in words
#define TW 1552           // per-tile buffer: 38x40 = 1520 used, 16-word pad tail

typedef float v2f __attribute__((ext_vector_type(2)));
typedef __attribute__((address_space(3))) void lds_t;
typedef __attribute__((address_space(1))) const void gm_t;

__global__ void filter_prep(const float* __restrict__ filt, float* __restrict__ ws)
{
    int t = threadIdx.x;                 // scalar tap index 0..143
    if (t < 144) {
        int n = t % 6, m = (t / 6) % 6, px = (t / 36) & 1, py = t / 72;
        float f = 4.0f * filt[(11 - py - 2 * m) * 12 + (11 - px - 2 * n)];
        ws[2 * t]     = f;               // duplicated (f,f) pair for v_pk_fma
        ws[2 * t + 1] = f;
    }
}

__global__ __launch_bounds__(256, 4) void upsample2d_kernel(
    const float* __restrict__ x, const v2f* __restrict__ ftp,
    float* __restrict__ out)
{
    __shared__ float s_in[2 * TW];        // 12416 B: two block-shared tile slabs

    const int tx = threadIdx.x, ty = threadIdx.y;
    const int w    = ty >> 2;             // wave id 0..3
    const int lane = (ty & 3) * 16 + tx;  // HW lane id within wave
    const int bc0 = blockIdx.z;           // batch b=bc0>>6 (0..1), chan=bc0&63
    const int boy = blockIdx.y, box = blockIdx.x;

    // ---- block-shared slab: rows 0..37 = x rows boy*32-3 .. +34, cols -3..+36 ----
    // wave w stages words [384w, 384w+384): 6 chunks of 64 lanes
    int goff[6];
    #pragma unroll
    for (int k = 0; k < 6; ++k) {
        int j = w * 384 + 64 * k + lane;  // slab word 0..1535
        if (j > 1519) j = 1519;           // tail: duplicate source, dest lands in pad
        int r = (j * 1639) >> 16;         // j / 40 (exact for j < 2700)
        int c = j - r * 40;
        int gy = boy * 32 - 3 + r, gx = box * 32 - 3 + c;
        gy = gy < 0 ? -gy : gy;  gy = gy > 255 ? 510 - gy : gy;
        gx = gx < 0 ? -gx : gx;  gx = gx > 255 ? 510 - gx : gx;
        goff[k] = gy * 256 + gx;
    }

    const float* x0 = x + (size_t)bc0 * 65536;            // batch b
    const float* x1 = x0 + (size_t)128 * 65536;           // batch b+2

    // ---- issue ALL staging up front: 6 chunks tile0, 6 chunks tile1 ----
    #pragma unroll
    for (int k = 0; k < 6; ++k)
        __builtin_amdgcn_global_load_lds((gm_t*)(x0 + goff[k]),
                                         (lds_t*)(s_in + w * 384 + 64 * k), 4, 0, 0);
    #pragma unroll
    for (int k = 0; k < 6; ++k)
        __builtin_amdgcn_global_load_lds((gm_t*)(x1 + goff[k]),
                                         (lds_t*)(s_in + TW + w * 384 + 64 * k), 4, 0, 0);

    const int xb  = (2 * ty) * S + 2 * tx;   // thread window: slab rows 2ty..2ty+7
    const int OY0 = boy * 64 + 4 * ty;
    const int OX  = box * 64 + 4 * tx;

    // ---- per-tile compute+store: R13's exact proven core ----
    auto tile = [&](const int sbase, float* oc) {
        v2f accp[4][2] = {};              // (out[oy][px], out[oy][2+px])
        #pragma unroll
        for (int r = 0; r < 8; ++r) {
            const int rb = sbase + xb + r * S;
            v2f e[4], o[3];
            #pragma unroll
            for (int j = 0; j < 4; ++j)   // even pairs: cols (2j, 2j+1)
                e[j] = *reinterpret_cast<const v2f*>(&s_in[rb + 2 * j]);
            #pragma unroll
            for (int j = 0; j < 3; ++j) { // odd pairs from LDS (proven form)
                o[j].x = s_in[rb + 2 * j + 1];
                o[j].y = s_in[rb + 2 * j + 2];
            }
            #pragma unroll
            for (int qy = 0; qy < 2; ++qy)
            #pragma unroll
            for (int py = 0; py < 2; ++py) {
                const int m = r - qy - py;
                if (m >= 0 && m <= 5) {
                    #pragma unroll
                    for (int px = 0; px < 2; ++px)
                    #pragma unroll
                    for (int n = 0; n < 6; ++n) {
                        const int c = px + n;
                        const v2f xp = (c & 1) ? o[(c - 1) >> 1] : e[c >> 1];
                        const v2f f2 = ftp[((py * 2 + px) * 6 + m) * 6 + n];
                        accp[2 * qy + py][px] =
                            __builtin_elementwise_fma(xp, f2, accp[2 * qy + py][px]);
                    }
                }
            }
        }
        #pragma unroll
        for (int oy = 0; oy < 4; ++oy) {
            float4 v = make_float4(accp[oy][0].x, accp[oy][1].x,
                                   accp[oy][0].y, accp[oy][1].y);
            *reinterpret_cast<float4*>(&oc[(size_t)(OY0 + oy) * 512 + OX]) = v;
        }
    };

    // tile 0: own 6 loads done -> barrier => ALL waves' tile0 chunks landed.
    // tile1's 6 loads remain in flight across the barrier (raw s_barrier: no drain).
    asm volatile("s_waitcnt vmcnt(6)" ::: "memory");
    __builtin_amdgcn_sched_barrier(0);
    __builtin_amdgcn_s_barrier();
    __builtin_amdgcn_sched_barrier(0);
    tile(0, out + (size_t)bc0 * 262144);

    // tile 1: outstanding = 6 tile1-loads (oldest) + 16 tile0-stores.
    // vmcnt(16): in-order retire => the 6 loads completed; stores not drained.
    asm volatile("s_waitcnt vmcnt(16)" ::: "memory");
    __builtin_amdgcn_sched_barrier(0);
    __builtin_amdgcn_s_barrier();
    __builtin_amdgcn_sched_barrier(0);
    tile(TW, out + (size_t)(bc0 + 128) * 262144);
}

extern "C" void kernel_launch(void* const* d_in, const int* in_sizes, int n_in,
                              void* d_out, int out_size, void* d_ws, size_t ws_size,
                              hipStream_t stream) {
    const float* x    = (const float*)d_in[0];   // (4,64,256,256) fp32
    const float* filt = (const float*)d_in[1];   // (12,12) fp32
    float* out = (float*)d_out;                  // (4,64,512,512) fp32
    float* ws  = (float*)d_ws;                   // 1152 B duplicated filter table

    filter_prep<<<dim3(1), dim3(256), 0, stream>>>(filt, ws);

    dim3 grid(8, 8, 128);   // 8x8 tiles; z = (batch 0..1, channel); +batch+2 in-kernel
    dim3 block(16, 16, 1);
    upsample2d_kernel<<<grid, block, 0, stream>>>(x, (const v2f*)ws, out);
}